// Round 1
// 534.415 us; speedup vs baseline: 1.0604x; 1.0604x over previous
//
#include <hip/hip_runtime.h>
#include <hip/hip_bf16.h>

// Problem constants (fixed by the reference)
#define DD   768
#define TT   1024
#define BBATCH 16
#define NROWS (BBATCH * TT)   // 16384
#define HIDN 3072
#define HHALF 1536
#define HH 32
#define WW 32
#define DW  (DD * DD)         // 589824
#define DH  (DD * HIDN)       // 2359296
#define CCH 64                // wkv chunk length
#define PCH (TT / CCH)        // 16 chunks

typedef float  floatx4 __attribute__((ext_vector_type(4)));
typedef __bf16 bf16x8  __attribute__((ext_vector_type(8)));

__device__ __forceinline__ float bf2f(__hip_bfloat16 v) { return __bfloat162float(v); }
__device__ __forceinline__ __hip_bfloat16 f2bf(float v) { return __float2bfloat16(v); }
__device__ __forceinline__ float toF(__hip_bfloat16 v) { return __bfloat162float(v); }
__device__ __forceinline__ float toF(float v) { return v; }

__device__ __forceinline__ void load4f(const float* __restrict__ p, float o[4]) {
    const float4 v = *reinterpret_cast<const float4*>(p);
    o[0] = v.x; o[1] = v.y; o[2] = v.z; o[3] = v.w;
}
__device__ __forceinline__ void load4f(const __hip_bfloat16* __restrict__ p, float o[4]) {
    const ushort4 v = *reinterpret_cast<const ushort4*>(p);
    o[0] = bf2f(__hip_bfloat16_raw{v.x});
    o[1] = bf2f(__hip_bfloat16_raw{v.y});
    o[2] = bf2f(__hip_bfloat16_raw{v.z});
    o[3] = bf2f(__hip_bfloat16_raw{v.w});
}

// global -> LDS direct DMA, 16 B per lane, dest = uniform base + lane*16
#define GL2LDS(gp, lp)  __builtin_amdgcn_global_load_lds(                     \
    (const __attribute__((address_space(1))) void*)(gp),                      \
    (__attribute__((address_space(3))) void*)(lp), 16, 0, 0)

// ---------------------------------------------------------------------------
// fp32 -> bf16 conversion of ALL weights in one dispatch (7 segments).
// dst layout: [Wk|Wv|Wr|Wo|Cr] (DW each) then [Ck|Cv] (DH each).
// ---------------------------------------------------------------------------
__global__ __launch_bounds__(256)
void cvt_all(const float* __restrict__ w0, const float* __restrict__ w1,
             const float* __restrict__ w2, const float* __restrict__ w3,
             const float* __restrict__ w4, const float* __restrict__ w5,
             const float* __restrict__ w6, __hip_bfloat16* __restrict__ dst)
{
    const int b = blockIdx.x;
    const float* s; size_t dofs; int rel;
    if (b < 2880) {            // 5 x 576 blocks of DW
        const int seg = b / 576; rel = b - seg * 576;
        s = seg == 0 ? w0 : seg == 1 ? w1 : seg == 2 ? w2 : seg == 3 ? w3 : w4;
        dofs = (size_t)seg * DW;
    } else if (b < 5184) {     // Ck: 2304 blocks
        rel = b - 2880; s = w5; dofs = 5ull * DW;
    } else {                   // Cv: 2304 blocks
        rel = b - 5184; s = w6; dofs = 5ull * DW + DH;
    }
    const int i = rel * 1024 + threadIdx.x * 4;
    const float4 v = *reinterpret_cast<const float4*>(s + i);
    __hip_bfloat16 o[4] = {f2bf(v.x), f2bf(v.y), f2bf(v.z), f2bf(v.w)};
    *reinterpret_cast<ushort4*>(&dst[dofs + i]) = *reinterpret_cast<const ushort4*>(o);
}

// ---------------------------------------------------------------------------
// Per-row LN stats: one 64-lane wave per row, 12 elems/lane via 4-wide
// vector loads (coalesced). 4 rows per 256-thread block. No LDS/barrier.
// ---------------------------------------------------------------------------
template <typename TIN>
__global__ __launch_bounds__(256)
void ln_stats_k(const TIN* __restrict__ x,
                float* __restrict__ mean, float* __restrict__ rstd)
{
    const int row  = blockIdx.x * 4 + (threadIdx.x >> 6);
    const int lane = threadIdx.x & 63;
    const TIN* xr = x + (size_t)row * DD;
    float s1 = 0.f, s2 = 0.f;
#pragma unroll
    for (int q = 0; q < 3; ++q) {
        float v4[4];
        load4f(xr + 4 * lane + 256 * q, v4);
#pragma unroll
        for (int e = 0; e < 4; ++e) { s1 += v4[e]; s2 += v4[e] * v4[e]; }
    }
#pragma unroll
    for (int off = 32; off > 0; off >>= 1) {
        s1 += __shfl_down(s1, off);
        s2 += __shfl_down(s2, off);
    }
    if (lane == 0) {
        const float m = s1 * (1.f / DD);
        mean[row] = m;
        rstd[row] = rsqrtf(s2 * (1.f / DD) - m * m + 1e-5f);
    }
}

// ---------------------------------------------------------------------------
// LN-on-the-fly + q_shift + token-mix, 4 consecutive channels per thread
// (float4 / ushort4 loads, ushort4 stores). 192 % 4 == 0 so the shift
// group is uniform across the 4 channels.
// ---------------------------------------------------------------------------
template <typename TIN, int NOUT>
__global__ __launch_bounds__(256)
void mix_k(const TIN* __restrict__ x,
           const float* __restrict__ mean, const float* __restrict__ rstd,
           const float* __restrict__ g, const float* __restrict__ b,
           const float* __restrict__ muk,
           const float* __restrict__ muv,   // unused if NOUT==2
           const float* __restrict__ mur,
           __hip_bfloat16* __restrict__ xk,
           __hip_bfloat16* __restrict__ xv, // unused if NOUT==2
           __hip_bfloat16* __restrict__ xr)
{
    const size_t i4 = ((size_t)blockIdx.x * 256 + threadIdx.x) * 4;
    const int c  = (int)(i4 % DD);
    const int n  = (int)((i4 / DD) % TT);
    const int bb = (int)(i4 / ((size_t)DD * TT));
    const int y = n >> 5, xp = n & 31;
    const int grow = bb * TT + n;

    const int grp = c / (DD / 4);
    int ny = y, nx = xp; bool ok;
    if      (grp == 0) { nx = xp - 1; ok = xp > 0;      }
    else if (grp == 1) { nx = xp + 1; ok = xp < WW - 1; }
    else if (grp == 2) { ny = y - 1;  ok = y > 0;       }
    else               { ny = y + 1;  ok = y < HH - 1;  }

    const float4 gv = *reinterpret_cast<const float4*>(g + c);
    const float4 bv = *reinterpret_cast<const float4*>(b + c);
    const float gg[4] = {gv.x, gv.y, gv.z, gv.w};
    const float bbv[4] = {bv.x, bv.y, bv.z, bv.w};

    float xc[4];
    load4f(x + (size_t)grow * DD + c, xc);
    const float m = mean[grow], rs = rstd[grow];
    float av[4], sx[4] = {0.f, 0.f, 0.f, 0.f};
#pragma unroll
    for (int e = 0; e < 4; ++e) av[e] = (xc[e] - m) * rs * gg[e] + bbv[e];

    if (ok) {
        const int nrow = bb * TT + ny * WW + nx;
        float xn[4];
        load4f(x + (size_t)nrow * DD + c, xn);
        const float m2 = mean[nrow], rs2 = rstd[nrow];
#pragma unroll
        for (int e = 0; e < 4; ++e) sx[e] = (xn[e] - m2) * rs2 * gg[e] + bbv[e];
    }

    const float4 mkv = *reinterpret_cast<const float4*>(muk + c);
    const float4 mrv = *reinterpret_cast<const float4*>(mur + c);
    const float mk[4] = {mkv.x, mkv.y, mkv.z, mkv.w};
    const float mr[4] = {mrv.x, mrv.y, mrv.z, mrv.w};
    __hip_bfloat16 ok4[4], or4[4];
#pragma unroll
    for (int e = 0; e < 4; ++e) {
        ok4[e] = f2bf(av[e] * mk[e] + sx[e] * (1.f - mk[e]));
        or4[e] = f2bf(av[e] * mr[e] + sx[e] * (1.f - mr[e]));
    }
    *reinterpret_cast<ushort4*>(&xk[i4]) = *reinterpret_cast<const ushort4*>(ok4);
    *reinterpret_cast<ushort4*>(&xr[i4]) = *reinterpret_cast<const ushort4*>(or4);
    if (NOUT == 3) {
        const float4 mvv = *reinterpret_cast<const float4*>(muv + c);
        const float mv[4] = {mvv.x, mvv.y, mvv.z, mvv.w};
        __hip_bfloat16 ov4[4];
#pragma unroll
        for (int e = 0; e < 4; ++e)
            ov4[e] = f2bf(av[e] * mv[e] + sx[e] * (1.f - mv[e]));
        *reinterpret_cast<ushort4*>(&xv[i4]) = *reinterpret_cast<const ushort4*>(ov4);
    }
}

// ---------------------------------------------------------------------------
// GEMM core: 128x128 tile, 4 waves (2x2 of 64x64), BK=64, global_load_lds
// staging with XOR col-group swizzle (round-6 verified: 0 bank conflicts).
// lds layout: A tile at [0, 8192), B tile at [8192, 16384) ushorts.
// ---------------------------------------------------------------------------
#define BM 128
#define BN 128
#define BKK 64

__device__ __forceinline__ void gemm_core(
    const __hip_bfloat16* __restrict__ A, const __hip_bfloat16* __restrict__ W,
    int K, int Wstr, int bm, int bn, unsigned short* lds, floatx4 acc[4][4])
{
    const int tid  = threadIdx.x;
    const int lane = tid & 63, wid = tid >> 6;
    const int l15  = lane & 15, quad = lane >> 4;
    const int m0   = (wid & 1) * 64;
    const int n0   = (wid >> 1) * 64;
    const int srow  = lane >> 3;            // 0..7
    const int gcolg = (lane & 7) ^ srow;    // swizzled col-group to fetch
    const int s0    = wid * 4;
    const int swzbase = l15 & 7;

    for (int k0 = 0; k0 < K; k0 += BKK) {
#pragma unroll
        for (int t = 0; t < 4; ++t) {
            const int s   = s0 + t;
            const int row = s * 8 + srow;
            GL2LDS(A + (size_t)(bm * BM + row) * K    + k0 + gcolg * 8,
                   &lds[s * 512]);
            GL2LDS(W + (size_t)(bn * BN + row) * Wstr + k0 + gcolg * 8,
                   &lds[8192 + s * 512]);
        }
        __syncthreads();
#pragma unroll
        for (int kk = 0; kk < BKK; kk += 32) {
            const int swz = (((kk >> 3) + quad) ^ swzbase) * 8;
            bf16x8 af[4], bfr[4];
#pragma unroll
            for (int i = 0; i < 4; ++i)
                af[i] = *reinterpret_cast<const bf16x8*>(
                    &lds[(m0 + i * 16 + l15) * BKK + swz]);
#pragma unroll
            for (int j = 0; j < 4; ++j)
                bfr[j] = *reinterpret_cast<const bf16x8*>(
                    &lds[8192 + (n0 + j * 16 + l15) * BKK + swz]);
#pragma unroll
            for (int i = 0; i < 4; ++i)
#pragma unroll
                for (int j = 0; j < 4; ++j)
                    acc[i][j] = __builtin_amdgcn_mfma_f32_16x16x32_bf16(
                        af[i], bfr[j], acc[i][j], 0, 0, 0);
        }
        __syncthreads();
    }
}

// Wave-private LDS transpose of one 16-row acc band -> 16 contiguous cols
// per lane (row_l = lane>>2, cols cb..cb+15). Wave-internal DS ops are
// in-order, so no barrier is needed; LDS tiles are dead after the K-loop's
// final barrier. Stride 68 floats keeps float4 alignment + <=2-way banks.
__device__ __forceinline__ void xpose_band(const floatx4 accRow[4], float* scr,
                                           int lane, float cv[16])
{
    const int l15 = lane & 15, quad = lane >> 4;
#pragma unroll
    for (int j = 0; j < 4; ++j)
#pragma unroll
        for (int r = 0; r < 4; ++r)
            scr[(quad * 4 + r) * 68 + j * 16 + l15] = accRow[j][r];
    const int row_l = lane >> 2, cb = (lane & 3) * 16;
#pragma unroll
    for (int q = 0; q < 4; ++q)
        *reinterpret_cast<float4*>(&cv[q * 4]) =
            *reinterpret_cast<const float4*>(&scr[row_l * 68 + cb + q * 4]);
}

// MODE: 1=bf16(sigmoid), 2=bf16(acc + xf32), 3=bf16(relu^2),
//       4=f32 out = h + s*acc + x   (s bf16 from auxS)
//       5=f32 out += s*acc
//       6=f32 out = h + gf*acc + x  (gf fp32 from auxG; auxG may be out itself:
//                                    each block reads only its own output tile)
//       7=f32 out = sigmoid(acc)
template <int MODE>
__global__ __launch_bounds__(256, 2)
void gemm_bt(const __hip_bfloat16* __restrict__ A,
             const __hip_bfloat16* __restrict__ W,
             int K, int Wstr, int Nn,
             __hip_bfloat16* __restrict__ outB,
             float* __restrict__ outF,
             const __hip_bfloat16* __restrict__ auxS,  // sigmoid gate bf16 [4,5]
             const __hip_bfloat16* __restrict__ auxH,  // h bf16       [4,6]
             const float* __restrict__ auxX,           // x fp32       [2,4,6]
             const float* __restrict__ auxG)           // gate fp32    [6]
{
    __shared__ __align__(16) unsigned short lds[16384];  // 32 KB
    const int bm = blockIdx.x, bn = blockIdx.y;
    const int tid = threadIdx.x, lane = tid & 63, wid = tid >> 6;
    const int m0 = (wid & 1) * 64, n0 = (wid >> 1) * 64;

    floatx4 acc[4][4];
#pragma unroll
    for (int i = 0; i < 4; ++i)
#pragma unroll
        for (int j = 0; j < 4; ++j)
            acc[i][j] = floatx4{0.f, 0.f, 0.f, 0.f};

    gemm_core(A, W, K, Wstr, bm, bn, lds, acc);

    float* scr = reinterpret_cast<float*>(lds) + wid * 1088;  // 4352 B/wave
    const int row_l = lane >> 2, cb = (lane & 3) * 16;
#pragma unroll
    for (int i = 0; i < 4; ++i) {
        float cv[16];
        xpose_band(acc[i], scr, lane, cv);
        const int grow = bm * BM + m0 + i * 16 + row_l;
        const int gcol = bn * BN + n0 + cb;
        const size_t idx = (size_t)grow * Nn + gcol;
        if (MODE == 1 || MODE == 3) {
            __hip_bfloat16 ob[16];
#pragma unroll
            for (int e = 0; e < 16; ++e) {
                float v = cv[e];
                if (MODE == 1) v = 1.f / (1.f + __expf(-v));
                else { v = fmaxf(v, 0.f); v = v * v; }
                ob[e] = f2bf(v);
            }
            *reinterpret_cast<uint4*>(&outB[idx])     = *reinterpret_cast<const uint4*>(&ob[0]);
            *reinterpret_cast<uint4*>(&outB[idx + 8]) = *reinterpret_cast<const uint4*>(&ob[8]);
        } else if (MODE == 2) {
            float xv[16];
#pragma unroll
            for (int q = 0; q < 4; ++q)
                *reinterpret_cast<float4*>(&xv[q * 4]) =
                    *reinterpret_cast<const float4*>(&auxX[idx + q * 4]);
            __hip_bfloat16 ob[16];
#pragma unroll
            for (int e = 0; e < 16; ++e) ob[e] = f2bf(cv[e] + xv[e]);
            *reinterpret_cast<uint4*>(&outB[idx])     = *reinterpret_cast<const uint4*>(&ob[0]);
            *reinterpret_cast<uint4*>(&outB[idx + 8]) = *reinterpret_cast<const uint4*>(&ob[8]);
        } else if (MODE == 4) {
            unsigned short hs[16], ss[16]; float xv[16], ov[16];
            *reinterpret_cast<uint4*>(&hs[0]) = *reinterpret_cast<const uint4*>(&auxH[idx]);
            *reinterpret_cast<uint4*>(&hs[8]) = *reinterpret_cast<const uint4*>(&auxH[idx + 8]);
            *reinterpret_cast<uint4*>(&ss[0]) = *reinterpret_cast<const uint4*>(&auxS[idx]);
            *reinterpret_cast<uint4*>(&ss[8]) = *reinterpret_cast<const uint4*>(&auxS[idx + 8]);
#pragma unroll
            for (int q = 0; q < 4; ++q)
                *reinterpret_cast<float4*>(&xv[q * 4]) =
                    *reinterpret_cast<const float4*>(&auxX[idx + q * 4]);
#pragma unroll
            for (int e = 0; e < 16; ++e)
                ov[e] = bf2f(__hip_bfloat16_raw{hs[e]})
                      + bf2f(__hip_bfloat16_raw{ss[e]}) * cv[e] + xv[e];
#pragma unroll
            for (int q = 0; q < 4; ++q)
                *reinterpret_cast<float4*>(&outF[idx + q * 4]) =
                    *reinterpret_cast<const float4*>(&ov[q * 4]);
        } else if (MODE == 5) {  // out += s*acc
            unsigned short ss[16]; float ov[16];
            *reinterpret_cast<uint4*>(&ss[0]) = *reinterpret_cast<const uint4*>(&auxS[idx]);
            *reinterpret_cast<uint4*>(&ss[8]) = *reinterpret_cast<const uint4*>(&auxS[idx + 8]);
#pragma unroll
            for (int q = 0; q < 4; ++q)
                *reinterpret_cast<float4*>(&ov[q * 4]) =
                    *reinterpret_cast<const float4*>(&outF[idx + q * 4]);
#pragma unroll
            for (int e = 0; e < 16; ++e)
                ov[e] += bf2f(__hip_bfloat16_raw{ss[e]}) * cv[e];
#pragma unroll
            for (int q = 0; q < 4; ++q)
                *reinterpret_cast<float4*>(&outF[idx + q * 4]) =
                    *reinterpret_cast<const float4*>(&ov[q * 4]);
        } else if (MODE == 6) {  // out = h + gf*acc + x, gate fp32
            unsigned short hs[16]; float xv[16], gf[16], ov[16];
            *reinterpret_cast<uint4*>(&hs[0]) = *reinterpret_cast<const uint4*>(&auxH[idx]);
            *reinterpret_cast<uint4*>(&hs[8]) = *reinterpret_cast<const uint4*>(&auxH[idx + 8]);
#pragma unroll
            for (int q = 0; q < 4; ++q) {
                *reinterpret_cast<float4*>(&xv[q * 4]) =
                    *reinterpret_cast<const float4*>(&auxX[idx + q * 4]);
                *reinterpret_cast<float4*>(&gf[q * 4]) =
                    *reinterpret_cast<const float4*>(&auxG[idx + q * 4]);
            }
#pragma unroll
            for (int e = 0; e < 16; ++e)
                ov[e] = bf2f(__hip_bfloat16_raw{hs[e]}) + gf[e] * cv[e] + xv[e];
#pragma unroll
            for (int q = 0; q < 4; ++q)
                *reinterpret_cast<float4*>(&outF[idx + q * 4]) =
                    *reinterpret_cast<const float4*>(&ov[q * 4]);
        } else {  // MODE 7: out = sigmoid(acc) fp32
            float ov[16];
#pragma unroll
            for (int e = 0; e < 16; ++e)
                ov[e] = 1.f / (1.f + __expf(-cv[e]));
#pragma unroll
            for (int q = 0; q < 4; ++q)
                *reinterpret_cast<float4*>(&outF[idx + q * 4]) =
                    *reinterpret_cast<const float4*>(&ov[q * 4]);
        }
    }
}

// Batched QKV: z=0 -> k, z=1 -> v, z=2 -> r=sigmoid(xr@Wr^T)
__global__ __launch_bounds__(256, 2)
void gemm_qkv(const __hip_bfloat16* __restrict__ A0, const __hip_bfloat16* __restrict__ A1,
              const __hip_bfloat16* __restrict__ A2,
              const __hip_bfloat16* __restrict__ W0, const __hip_bfloat16* __restrict__ W1,
              const __hip_bfloat16* __restrict__ W2,
              __hip_bfloat16* __restrict__ O0, __hip_bfloat16* __restrict__ O1,
              __hip_bfloat16* __restrict__ O2)
{
    __shared__ __align__(16) unsigned short lds[16384];
    const int z = blockIdx.z;
    const __hip_bfloat16* A = z == 0 ? A0 : z == 1 ? A1 : A2;
    const __hip_bfloat16* W = z == 0 ? W0 : z == 1 ? W1 : W2;
    __hip_bfloat16*       O = z == 0 ? O0 : z == 1 ? O1 : O2;
    const int bm = blockIdx.x, bn = blockIdx.y;
    const int tid = threadIdx.x, lane = tid & 63, wid = tid >> 6;
    const int m0 = (wid & 1) * 64, n0 = (wid >> 1) * 64;

    floatx4 acc[4][4];
#pragma unroll
    for (int i = 0; i < 4; ++i)
#pragma unroll
        for (int j = 0; j < 4; ++j)
            acc[i][j] = floatx4{0.f, 0.f, 0.f, 0.f};

    gemm_core(A, W, DD, DD, bm, bn, lds, acc);

    float* scr = reinterpret_cast<float*>(lds) + wid * 1088;
    const int row_l = lane >> 2, cb = (lane & 3) * 16;
#pragma unroll
    for (int i = 0; i < 4; ++i) {
        float cv[16];
        xpose_band(acc[i], scr, lane, cv);
        const int grow = bm * BM + m0 + i * 16 + row_l;
        const int gcol = bn * BN + n0 + cb;
        const size_t idx = (size_t)grow * DD + gcol;
        __hip_bfloat16 ob[16];
#pragma unroll
        for (int e = 0; e < 16; ++e) {
            float v = cv[e];
            if (z == 2) v = 1.f / (1.f + __expf(-v));
            ob[e] = f2bf(v);
        }
        *reinterpret_cast<uint4*>(&O[idx])     = *reinterpret_cast<const uint4*>(&ob[0]);
        *reinterpret_cast<uint4*>(&O[idx + 8]) = *reinterpret_cast<const uint4*>(&ob[8]);
    }
}

// ---------------------------------------------------------------------------
// WKV parallel scan over T (chunked two-pass; round-5 verified).
// ---------------------------------------------------------------------------
__global__ __launch_bounds__(256)
void wkv_passA(const float* __restrict__ w_log,
               const __hip_bfloat16* __restrict__ k,
               const __hip_bfloat16* __restrict__ v,
               float* __restrict__ SA, float* __restrict__ SB,
               float* __restrict__ SP)
{
    const int c  = blockIdx.x * 256 + threadIdx.x;  // 0..767
    const int j  = blockIdx.y;                      // chunk
    const int bb = blockIdx.z;                      // batch
    const float w = -__expf(w_log[c]);
    const size_t base = ((size_t)bb * TT + j * CCH) * DD + c;
    float a = 0.f, b = 0.f, p = -1e30f;
#pragma unroll 4
    for (int t = 0; t < CCH; ++t) {
        const size_t o = base + (size_t)t * DD;
        const float kt = bf2f(k[o]);
        const float vt = bf2f(v[o]);
        const float ww2 = p + w;
        const float p2  = fmaxf(ww2, kt);
        const float e1  = __expf(ww2 - p2);
        const float e2  = __expf(kt - p2);
        a = e1 * a + e2 * vt;
        b = e1 * b + e2;
        p = p2;
    }
    const size_t si = ((size_t)bb * PCH + j) * DD + c;
    SA[si] = a; SB[si] = b; SP[si] = p;
}

__global__ __launch_bounds__(256)
void wkv_scanj(const float* __restrict__ w_log,
               float* __restrict__ SA, float* __restrict__ SB,
               float* __restrict__ SP)
{
    const int idx = blockIdx.x * 256 + threadIdx.x;  // 0..B*D-1
    const int c = idx % DD, bb = idx / DD;
    const float wC = -__expf(w_log[c]) * (float)CCH;  // decay over one chunk
    float a = 0.f, b = 0.f, p = -1e30f;
#pragma unroll
    for (int j = 0; j < PCH; ++j) {
        const size_t si = ((size_t)bb * PCH + j) * DD + c;
        const float aj = SA[si], bj = SB[si], pj = SP[si];
        SA[si] = a; SB[si] = b; SP[si] = p;   // exclusive prefix (chunk input)
        const float pd = p + wC;
        const float pn = fmaxf(pd, pj);
        const float e1 = __expf(pd - pn);
        const float e2 = __expf(pj - pn);
        a = e1 * a + e2 * aj;
        b = e1 * b + e2 * bj;
        p = pn;
    }
}

__global__ __launch_bounds__(256)
void wkv_passB(const float* __restrict__ w_log, const float* __restrict__ u,
               const __hip_bfloat16* __restrict__ k,
               const __hip_bfloat16* __restrict__ v,
               const __hip_bfloat16* __restrict__ r,
               __hip_bfloat16* __restrict__ rw,
               const float* __restrict__ SA, const float* __restrict__ SB,
               const float* __restrict__ SP)
{
    const int c  = blockIdx.x * 256 + threadIdx.x;
    const int j  = blockIdx.y;
    const int bb = blockIdx.z;
    const float w  = -__expf(w_log[c]);
    const float uu = u[c];
    const size_t si = ((size_t)bb * PCH + j) * DD + c;
    float aa = SA[si], bbv = SB[si], pp = SP[si];
    const size_t base = ((size_t)bb * TT + j * CCH) * DD + c;
#pragma unroll 4
    for (int t = 0; t < CCH; ++t) {
        const size_t o = base + (size_t)t * DD;
        const float kt = bf2f(k[o]);
        const float vt = bf2f(v[o]);
        const float rt = bf2f(r[o]);
        const float ww = uu + kt;
        const float p  = fmaxf(pp, ww);
        const float e1 = __expf(pp - p);
        const float e2 = __expf(ww - p);
        const float ov = __fdividef(e1 * aa + e2 * vt, e1 * bbv + e2);
        rw[o] = f2bf(rt * ov);
        const float ww2 = pp + w;
        const float p2  = fmaxf(ww2, kt);
        const float e1b = __expf(ww2 - p2);
        const float e2b = __expf(kt - p2);
        aa  = e1b * aa + e2b * vt;
        bbv = e1b * bbv + e2b;
        pp  = p2;
    }
}

// ---------------------------------------------------------------------------
extern "C" void kernel_launch(void* const* d_in, const int* in_sizes, int n_in,
                              void* d_out, int out_size, void* d_ws, size_t ws_size,
                              hipStream_t stream)
{
    (void)in_sizes; (void)n_in; (void)out_size;
    const float* x     = (const float*)d_in[0];
    // d_in[1]=H, d_in[2]=W (compile-time constants 32x32)
    const float* ln1_g = (const float*)d_in[3];
    const float* ln1_b = (const float*)d_in[4];
    const float* ln2_g = (const float*)d_in[5];
    const float* ln2_b = (const float*)d_in[6];
    const float* mu_k  = (const float*)d_in[7];
    const float* mu_v  = (const float*)d_in[8];
    const float* mu_r  = (const float*)d_in[9];
    const float* w_log = (const float*)d_in[10];
    const float* u     = (const float*)d_in[11];
    const float* Wk    = (const float*)d_in[12];
    const float* Wv    = (const float*)d_in[13];
    const float* Wr    = (const float*)d_in[14];
    const float* Wo    = (const float*)d_in[15];
    const float* cmu_k = (const float*)d_in[16];
    const float* cmu_r = (const float*)d_in[17];
    const float* Ck    = (const float*)d_in[18];
    const float* Cv    = (const float*)d_in[19];
    const float* Cr    = (const float*)d_in[20];
    float* out = (float*)d_out;

    // ---- workspace: N bf16 ND slots + bf16 weights + stats + scan states.
    // Adaptive slot count: 7 (full FFN merge + r batched), 6 (gate spilled to
    // d_out as fp32), 5 (previous verified schedule).
    const size_t ND = (size_t)NROWS * DD;   // 12,582,912 elements
    const size_t SL = ND * 2;               // 25,165,824 B per bf16 slot
    const size_t WBYTES = (size_t)(5 * DW + 2 * DH) * 2;  // 15,335,424
    const size_t NSTATE = (size_t)BBATCH * PCH * DD;      // 196,608
    const size_t TAIL = WBYTES + 2 * (size_t)NROWS * sizeof(float)
                      + 3 * NSTATE * sizeof(float);
    int nslots;
    if      (ws_size >= 7 * SL + TAIL) nslots = 7;   // ~194.0 MB
    else if (ws_size >= 6 * SL + TAIL) nslots = 6;   // ~168.8 MB
    else if (ws_size >= 5 * SL + TAIL) nslots = 5;   // ~143.7 MB (verified)
    else return;  // diagnostic: absmax-fail instead of fault

    char* w = (char*)d_ws;
    __hip_bfloat16* S0 = (__hip_bfloat16*)(w);
    __hip_bfloat16* S1 = (__hip_bfloat16*)(w + 1 * SL);
    __hip_bfloat16* S2 = (__hip_bfloat16*)(w + 2 * SL);
    __hip_bfloat16* S3 = (__hip_bfloat16*)(w + 3 * SL);
    __hip_bfloat16* S4 = (__hip_bfloat16*)(w + 4 * SL);
    __hip_bfloat16* S5 = (__hip_bfloat16*)(w + 5 * SL);  // valid iff nslots>=6
    __hip_bfloat16* WB  = (__hip_bfloat16*)(w + (size_t)nslots * SL);
    __hip_bfloat16* WkB = WB;
    __hip_bfloat16* WvB = WB + 1ull * DW;
    __hip_bfloat16* WrB = WB + 2ull * DW;
    __hip_bfloat16* WoB = WB + 3ull * DW;
    __hip_bfloat16* CrB = WB + 4ull * DW;
    __hip_bfloat16* CkB = WB + 5ull * DW;
    __hip_bfloat16* CvB = CkB + DH;
    float* meanB = (float*)(w + (size_t)nslots * SL + WBYTES);
    float* rstdB = meanB + NROWS;
    float* SAb = rstdB + NROWS;
    float* SBb = SAb + NSTATE;
    float* SPb = SBb + NSTATE;

    const int LN_GRID  = NROWS / 4;            // 4096 (wave-per-row x4)
    const int MIX_GRID = (int)(ND / 1024);     // 12288 (4 ch/thread)
    const dim3 g768(NROWS / BM, DD / BN);      // (128, 6)
    const dim3 g1536(NROWS / BM, HHALF / BN);  // (128, 12) fallback FFN halves
    const dim3 gCk(NROWS / BM, HIDN / BN);     // (128, 24) merged Ck
    const dim3 gqkv3(NROWS / BM, DD / BN, 3);
    const dim3 gqkv2(NROWS / BM, DD / BN, 2);
    const dim3 gwkv(DD / 256, PCH, BBATCH);    // (3, 16, 16)

    // ---- weight conversion (single dispatch) ----
    cvt_all<<<7488, 256, 0, stream>>>(Wk, Wv, Wr, Wo, Cr, Ck, Cv, WB);

    // ---- spatial mix: LN + shift + token-mix (shared by all paths) ----
    ln_stats_k<float><<<LN_GRID, 256, 0, stream>>>(x, meanB, rstdB);
    mix_k<float, 3><<<MIX_GRID, 256, 0, stream>>>(x, meanB, rstdB, ln1_g, ln1_b,
                                                  mu_k, mu_v, mu_r, S0, S1, S2);

    if (nslots == 7) {
        // k->S3, v->S4, r->S5 in one batched dispatch (all inputs/outputs disjoint)
        gemm_qkv<<<gqkv3, 256, 0, stream>>>(S0, S1, S2, WkB, WvB, WrB, S3, S4, S5);
        wkv_passA<<<gwkv, 256, 0, stream>>>(w_log, S3, S4, SAb, SBb, SPb);
        wkv_scanj<<<(BBATCH * DD) / 256, 256, 0, stream>>>(w_log, SAb, SBb, SPb);
        wkv_passB<<<gwkv, 256, 0, stream>>>(w_log, u, S3, S4, S5, S1, SAb, SBb, SPb); // rw->S1 (xv dead)
        gemm_bt<2><<<g768, 256, 0, stream>>>(S1, WoB, DD, DD, DD, S2, nullptr,
                                             nullptr, nullptr, x, nullptr);  // h->S2 (xr dead)
        // ---- channel mix ----
        ln_stats_k<__hip_bfloat16><<<LN_GRID, 256, 0, stream>>>(S2, meanB, rstdB);
        mix_k<__hip_bfloat16, 2><<<MIX_GRID, 256, 0, stream>>>(S2, meanB, rstdB, ln2_g, ln2_b,
                                                               cmu_k, nullptr, cmu_r,
                                                               S0, nullptr, S3);  // xk2->S0, xr2->S3
        gemm_bt<1><<<g768, 256, 0, stream>>>(S3, CrB, DD, DD, DD, S1, nullptr,
                                             nullptr, nullptr, nullptr, nullptr); // gate->S1 (rw dead)
        // merged FFN: kk (16384 x 3072 bf16 = 100 MB) in contiguous S3..S6
        gemm_bt<3><<<gCk, 256, 0, stream>>>(S0, CkB, DD, DD, HIDN,
                                            S3, nullptr, nullptr, nullptr, nullptr, nullptr);
        gemm_bt<4><<<g768, 256, 0, stream>>>(S3, CvB, HIDN, HIDN, DD,
                                             nullptr, out, S1, S2, x, nullptr);
    } else if (nslots == 6) {
        gemm_qkv<<<gqkv3, 256, 0, stream>>>(S0, S1, S2, WkB, WvB, WrB, S3, S4, S5);
        wkv_passA<<<gwkv, 256, 0, stream>>>(w_log, S3, S4, SAb, SBb, SPb);
        wkv_scanj<<<(BBATCH * DD) / 256, 256, 0, stream>>>(w_log, SAb, SBb, SPb);
        wkv_passB<<<gwkv, 256, 0, stream>>>(w_log, u, S3, S4, S5, S0, SAb, SBb, SPb); // rw->S0 (xk dead)
        gemm_bt<2><<<g768, 256, 0, stream>>>(S0, WoB, DD, DD, DD, S1, nullptr,
                                             nullptr, nullptr, x, nullptr);  // h->S1 (xv dead)
        // ---- channel mix ----
        ln_stats_k<__hip_bfloat16><<<LN_GRID, 256, 0, stream>>>(S1, meanB, rstdB);
        mix_k<__hip_bfloat16, 2><<<MIX_GRID, 256, 0, stream>>>(S1, meanB, rstdB, ln2_g, ln2_b,
                                                               cmu_k, nullptr, cmu_r,
                                                               S0, nullptr, S2);  // xk2->S0, xr2->S2
        // gate as fp32 parked in d_out (each MODE-6 block reads only its own tile)
        gemm_bt<7><<<g768, 256, 0, stream>>>(S2, CrB, DD, DD, DD, nullptr, out,
                                             nullptr, nullptr, nullptr, nullptr);
        // merged FFN: kk in contiguous S2..S5 (xr2 dead after Cr)
        gemm_bt<3><<<gCk, 256, 0, stream>>>(S0, CkB, DD, DD, HIDN,
                                            S2, nullptr, nullptr, nullptr, nullptr, nullptr);
        gemm_bt<6><<<g768, 256, 0, stream>>>(S2, CvB, HIDN, HIDN, DD,
                                             nullptr, out, nullptr, S1, x, out);
    } else {
        // ---- previous verified 5-slot schedule ----
        gemm_qkv<<<gqkv2, 256, 0, stream>>>(S0, S1, nullptr, WkB, WvB, nullptr,
                                            S3, S4, nullptr);       // k->S3, v->S4
        gemm_bt<1><<<g768, 256, 0, stream>>>(S2, WrB, DD, DD, DD, S0, nullptr,
                                             nullptr, nullptr, nullptr, nullptr); // r->S0
        wkv_passA<<<gwkv, 256, 0, stream>>>(w_log, S3, S4, SAb, SBb, SPb);
        wkv_scanj<<<(BBATCH * DD) / 256, 256, 0, stream>>>(w_log, SAb, SBb, SPb);
        wkv_passB<<<gwkv, 256, 0, stream>>>(w_log, u, S3, S4, S0, S1, SAb, SBb, SPb); // rw->S1
        gemm_bt<2><<<g768, 256, 0, stream>>>(S1, WoB, DD, DD, DD, S2, nullptr,
                                             nullptr, nullptr, x, nullptr);       // h->S2
        ln_stats_k<__hip_bfloat16><<<LN_GRID, 256, 0, stream>>>(S2, meanB, rstdB);
        mix_k<__hip_bfloat16, 2><<<MIX_GRID, 256, 0, stream>>>(S2, meanB, rstdB, ln2_g, ln2_b,
                                                               cmu_k, nullptr, cmu_r,
                                                               S0, nullptr, S3);
        gemm_bt<1><<<g768, 256, 0, stream>>>(S3, CrB, DD, DD, DD, S1, nullptr,
                                             nullptr, nullptr, nullptr, nullptr); // cr->S1
        __hip_bfloat16* kk = S3;  // FFN in two 1536-wide halves (kk in S3+S4)
        gemm_bt<3><<<g1536, 256, 0, stream>>>(S0, CkB, DD, DD, HHALF,
                                              kk, nullptr, nullptr, nullptr, nullptr, nullptr);
        gemm_bt<4><<<g768, 256, 0, stream>>>(kk, CvB, HHALF, HIDN, DD,
                                             nullptr, out, S1, S2, x, nullptr);
        gemm_bt<3><<<g1536, 256, 0, stream>>>(S0, CkB + (size_t)HHALF * DD, DD, DD, HHALF,
                                              kk, nullptr, nullptr, nullptr, nullptr, nullptr);
        gemm_bt<5><<<g768, 256, 0, stream>>>(kk, CvB + HHALF, HHALF, HIDN, DD,
                                             nullptr, out, S1, nullptr, nullptr, nullptr);
    }
}